// Round 5
// baseline (66.911 us; speedup 1.0000x reference)
//
#include <hip/hip_runtime.h>

#define BB 2
#define NN 512
#define DD 64
#define LN_EPS 1e-5f
#define NEG_SLOPE 0.01f

typedef float f32x4 __attribute__((ext_vector_type(4)));

__device__ __forceinline__ float wave_reduce_sum(float v) {
    #pragma unroll
    for (int off = 32; off >= 1; off >>= 1)
        v += __shfl_xor(v, off, 64);
    return v;
}

__device__ __forceinline__ float wave_reduce_max(float v) {
    #pragma unroll
    for (int off = 32; off >= 1; off >>= 1)
        v = fmaxf(v, __shfl_xor(v, off, 64));
    return v;
}

// One block per (b,i) row — 1024 blocks x 256 threads. Fully fused:
// setup (wave 0): gwq/gwk products -> LDS, scalar sums, c[b] from iid.
// phase A: thread t recomputes sk-dots for rows t, t+256 via the identity
//   LN(x).w = r*(dot(x, g*w) - m*sum(g*w)) + sum(beta*w), one pass per row.
// phase B: block softmax over 512 scores.
// phase C: stream both outputs (f32x4, fully coalesced, normal stores).
__global__ __launch_bounds__(256) void fused_kernel(
    const float* __restrict__ ua,
    const float* __restrict__ iid,
    const float* __restrict__ ln_g,
    const float* __restrict__ ln_b,
    const float* __restrict__ w_att,
    const float* __restrict__ b_att,
    float* __restrict__ out0,   // alphas broadcast [B,N,N,D]
    float* __restrict__ out1) { // value = q*k      [B,N,N,D]
    __shared__ f32x4 gwq_sh[DD / 4];
    __shared__ f32x4 gwk_sh[DD / 4];
    __shared__ float scal_sh[4];   // sgq, sbq, sgk, sbk
    __shared__ float sqc_sh[2];    // sq_i, c
    __shared__ float alpha_sh[NN];
    __shared__ float red_mx[4];
    __shared__ float red_sm[4];

    const int bid = blockIdx.x;
    const int b = bid >> 9;
    const int i = bid & (NN - 1);
    const int tid = threadIdx.x;

    // ---- setup: wave 0 only ----
    if (tid < DD) {
        const float g  = ln_g[tid];
        const float be = ln_b[tid];
        const float wq = w_att[tid];
        const float wk = w_att[DD + tid];
        const float wi = w_att[2 * DD + tid];
        ((float*)gwq_sh)[tid] = g * wq;
        ((float*)gwk_sh)[tid] = g * wk;
        const float sgq = wave_reduce_sum(g * wq);
        const float sbq = wave_reduce_sum(be * wq);
        const float sgk = wave_reduce_sum(g * wk);
        const float sbk = wave_reduce_sum(be * wk);
        // c[b] from iid, wave-parallel
        const float x = iid[b * DD + tid];
        const float m = wave_reduce_sum(x) * (1.0f / DD);
        const float xc = x - m;
        const float var = wave_reduce_sum(xc * xc) * (1.0f / DD);
        const float r = rsqrtf(var + LN_EPS);
        const float s3 = wave_reduce_sum((xc * r * g + be) * wi);
        if (tid == 0) {
            scal_sh[0] = sgq; scal_sh[1] = sbq;
            scal_sh[2] = sgk; scal_sh[3] = sbk;
            sqc_sh[1] = s3 + b_att[0];
        }
    }
    __syncthreads();

    const float sgq = scal_sh[0], sbq = scal_sh[1];
    const float sgk = scal_sh[2], sbk = scal_sh[3];

    const f32x4* __restrict__ uaB = (const f32x4*)(ua + (size_t)b * NN * DD);

    // ---- phase A: per-thread LN-dot for rows tid and tid+256 ----
    float dk0, dk1;
    #pragma unroll
    for (int rr = 0; rr < 2; ++rr) {
        const int j = tid + rr * 256;
        const f32x4* __restrict__ px = uaB + (size_t)j * 16;
        float sx = 0.f, sxx = 0.f, axk = 0.f, axq = 0.f;
        #pragma unroll
        for (int k = 0; k < 16; ++k) {
            const f32x4 x = px[k];
            const f32x4 gk = gwk_sh[k];
            const f32x4 gq = gwq_sh[k];
            sx  += x.x + x.y + x.z + x.w;
            sxx += x.x * x.x + x.y * x.y + x.z * x.z + x.w * x.w;
            axk += x.x * gk.x + x.y * gk.y + x.z * gk.z + x.w * gk.w;
            axq += x.x * gq.x + x.y * gq.y + x.z * gq.z + x.w * gq.w;
        }
        const float m = sx * (1.0f / DD);
        const float var = sxx * (1.0f / DD) - m * m;
        const float r = rsqrtf(var + LN_EPS);
        const float d = r * (axk - m * sgk) + sbk;
        if (rr == 0) dk0 = d; else dk1 = d;
        if (j == i) sqc_sh[0] = r * (axq - m * sgq) + sbq;
    }
    __syncthreads();

    // ---- phase B: softmax over 512 ----
    const float sqi = sqc_sh[0];
    const float c = sqc_sh[1];
    float s0 = sqi + dk0 + c;
    float s1 = sqi + dk1 + c;
    s0 = fmaxf(s0, NEG_SLOPE * s0);
    s1 = fmaxf(s1, NEG_SLOPE * s1);

    float mx = fmaxf(s0, s1);
    mx = wave_reduce_max(mx);
    const int wid = tid >> 6;
    if ((tid & 63) == 0) red_mx[wid] = mx;
    __syncthreads();
    mx = fmaxf(fmaxf(red_mx[0], red_mx[1]), fmaxf(red_mx[2], red_mx[3]));

    const float e0 = __expf(s0 - mx);
    const float e1 = __expf(s1 - mx);
    float sm = wave_reduce_sum(e0 + e1);
    if ((tid & 63) == 0) red_sm[wid] = sm;
    __syncthreads();
    sm = red_sm[0] + red_sm[1] + red_sm[2] + red_sm[3];
    const float inv = 1.0f / sm;

    alpha_sh[tid] = e0 * inv;
    alpha_sh[tid + 256] = e1 * inv;
    __syncthreads();

    // ---- phase C: stream both outputs, 8192 f32x4 each ----
    const int d4 = tid & 15;
    const f32x4 ui = uaB[(size_t)i * 16 + d4];
    f32x4* __restrict__ o0 = (f32x4*)(out0 + (size_t)bid * NN * DD);
    f32x4* __restrict__ o1 = (f32x4*)(out1 + (size_t)bid * NN * DD);

    #pragma unroll 4
    for (int k = 0; k < 32; ++k) {
        const int idx = tid + k * 256;
        const float a = alpha_sh[idx >> 4];
        const f32x4 uj = uaB[idx];
        f32x4 av;
        av.x = a; av.y = a; av.z = a; av.w = a;
        o0[idx] = av;
        o1[idx] = ui * uj;
    }
}

extern "C" void kernel_launch(void* const* d_in, const int* in_sizes, int n_in,
                              void* d_out, int out_size, void* d_ws, size_t ws_size,
                              hipStream_t stream) {
    const float* ua    = (const float*)d_in[0];
    const float* iid   = (const float*)d_in[1];
    const float* ln_g  = (const float*)d_in[2];
    const float* ln_b  = (const float*)d_in[3];
    const float* w_att = (const float*)d_in[4];
    const float* b_att = (const float*)d_in[5];

    float* out0 = (float*)d_out;                                // alphas [B,N,N,D]
    float* out1 = out0 + (size_t)BB * NN * NN * DD;             // value  [B,N,N,D]

    fused_kernel<<<BB * NN, 256, 0, stream>>>(ua, iid, ln_g, ln_b,
                                              w_att, b_att, out0, out1);
}

// Round 6
// 49.054 us; speedup vs baseline: 1.3640x; 1.3640x over previous
//
#include <hip/hip_runtime.h>

#define BB 2
#define NN 512
#define DD 64
#define LN_EPS 1e-5f
#define NEG_SLOPE 0.01f

typedef float f32x4 __attribute__((ext_vector_type(4)));

__device__ __forceinline__ float wave_reduce_sum(float v) {
    #pragma unroll
    for (int off = 32; off >= 1; off >>= 1)
        v += __shfl_xor(v, off, 64);
    return v;
}

__device__ __forceinline__ float wave_reduce_max(float v) {
    #pragma unroll
    for (int off = 32; off >= 1; off >>= 1)
        v = fmaxf(v, __shfl_xor(v, off, 64));
    return v;
}

// K1: streams out1 = ua_i * ua_j (no precompute dependency). Wave 0 of the
// first 1026 blocks additionally computes sq/sk (ua rows) or c (iid rows)
// into d_ws — hidden under the store stream.
__global__ __launch_bounds__(256) void value_kernel(
    const float* __restrict__ ua,
    const float* __restrict__ iid,
    const float* __restrict__ ln_g,
    const float* __restrict__ ln_b,
    const float* __restrict__ w_att,
    const float* __restrict__ b_att,
    float* __restrict__ sq,
    float* __restrict__ sk,
    float* __restrict__ cb,
    float* __restrict__ out1) {
    const int bid2 = blockIdx.x;
    const int tid = threadIdx.x;

    // ---- embedded precompute (wave 0, blocks 0..BB*NN+BB-1) ----
    if (tid < 64 && bid2 < BB * NN + BB) {
        const int lane = tid;
        const float g = ln_g[lane];
        const float bet = ln_b[lane];
        if (bid2 < BB * NN) {
            float x = ua[bid2 * DD + lane];
            float m = wave_reduce_sum(x) * (1.0f / DD);
            float xc = x - m;
            float var = wave_reduce_sum(xc * xc) * (1.0f / DD);
            float r = rsqrtf(var + LN_EPS);
            float w = xc * r * g + bet;
            float s1 = wave_reduce_sum(w * w_att[lane]);
            float s2 = wave_reduce_sum(w * w_att[DD + lane]);
            if (lane == 0) {
                sq[bid2] = s1;
                sk[bid2] = s2;
            }
        } else {
            int b = bid2 - BB * NN;
            float x = iid[b * DD + lane];
            float m = wave_reduce_sum(x) * (1.0f / DD);
            float xc = x - m;
            float var = wave_reduce_sum(xc * xc) * (1.0f / DD);
            float r = rsqrtf(var + LN_EPS);
            float w = xc * r * g + bet;
            float s3 = wave_reduce_sum(w * w_att[2 * DD + lane]);
            if (lane == 0) {
                cb[b] = s3 + b_att[0];
            }
        }
    }

    // ---- stream out1 for (row, half) ----
    const int row = bid2 >> 1;         // b*N + i
    const int half = bid2 & 1;
    const int b = row >> 9;
    const int i = row & (NN - 1);

    const f32x4* __restrict__ uaB = (const f32x4*)(ua + (size_t)b * NN * DD);
    const f32x4* __restrict__ uaH = uaB + (size_t)half * 256 * 16;
    const f32x4 ui = uaB[(size_t)i * 16 + (tid & 15)];

    f32x4* __restrict__ o1 =
        (f32x4*)(out1 + (size_t)row * NN * DD + (size_t)half * 256 * DD);

    #pragma unroll 4
    for (int k = 0; k < 16; ++k) {
        const int idx = tid + k * 256;   // d4 = idx&15 == tid&15
        o1[idx] = ui * uaH[idx];
    }
}

// K2: softmax from ws scalars, then pure alpha-broadcast store stream.
__global__ __launch_bounds__(256) void alpha_kernel(
    const float* __restrict__ sq,
    const float* __restrict__ sk,
    const float* __restrict__ cb,
    float* __restrict__ out0) {
    __shared__ float alpha_sh[256];
    __shared__ float red_mx[4];
    __shared__ float red_sm[4];

    const int bid2 = blockIdx.x;
    const int row = bid2 >> 1;
    const int half = bid2 & 1;
    const int b = row >> 9;
    const int tid = threadIdx.x;

    const float sqi = sq[row];
    const float c = cb[b];

    float s0 = sqi + sk[b * NN + tid] + c;
    float s1 = sqi + sk[b * NN + tid + 256] + c;
    s0 = fmaxf(s0, NEG_SLOPE * s0);
    s1 = fmaxf(s1, NEG_SLOPE * s1);

    float mx = fmaxf(s0, s1);
    mx = wave_reduce_max(mx);
    const int wid = tid >> 6;
    if ((tid & 63) == 0) red_mx[wid] = mx;
    __syncthreads();
    mx = fmaxf(fmaxf(red_mx[0], red_mx[1]), fmaxf(red_mx[2], red_mx[3]));

    const float e0 = __expf(s0 - mx);
    const float e1 = __expf(s1 - mx);
    float sm = wave_reduce_sum(e0 + e1);
    if ((tid & 63) == 0) red_sm[wid] = sm;
    __syncthreads();
    sm = red_sm[0] + red_sm[1] + red_sm[2] + red_sm[3];
    const float inv = 1.0f / sm;

    alpha_sh[tid] = (half ? e1 : e0) * inv;
    __syncthreads();

    f32x4* __restrict__ o0 =
        (f32x4*)(out0 + (size_t)row * NN * DD + (size_t)half * 256 * DD);

    #pragma unroll 4
    for (int k = 0; k < 16; ++k) {
        const int idx = tid + k * 256;
        const float a = alpha_sh[idx >> 4];
        f32x4 av;
        av.x = a; av.y = a; av.z = a; av.w = a;
        o0[idx] = av;
    }
}

extern "C" void kernel_launch(void* const* d_in, const int* in_sizes, int n_in,
                              void* d_out, int out_size, void* d_ws, size_t ws_size,
                              hipStream_t stream) {
    const float* ua    = (const float*)d_in[0];
    const float* iid   = (const float*)d_in[1];
    const float* ln_g  = (const float*)d_in[2];
    const float* ln_b  = (const float*)d_in[3];
    const float* w_att = (const float*)d_in[4];
    const float* b_att = (const float*)d_in[5];

    float* out0 = (float*)d_out;                                // alphas [B,N,N,D]
    float* out1 = out0 + (size_t)BB * NN * NN * DD;             // value  [B,N,N,D]

    float* sq = (float*)d_ws;          // B*N
    float* sk = sq + BB * NN;          // B*N
    float* cb = sk + BB * NN;          // B

    value_kernel<<<BB * NN * 2, 256, 0, stream>>>(ua, iid, ln_g, ln_b,
                                                  w_att, b_att, sq, sk, cb, out1);
    alpha_kernel<<<BB * NN * 2, 256, 0, stream>>>(sq, sk, cb, out0);
}